// Round 2
// baseline (9761.029 us; speedup 1.0000x reference)
//
#include <hip/hip_runtime.h>
#include <hip/hip_bf16.h>

#define HH 512
#define FF 128
#define BB 2048
#define TT 96
#define NGATE 2048
#define NTOT 2176
#define GRP 16
#define CPB 32

typedef short short8 __attribute__((ext_vector_type(8)));
typedef float f32x4 __attribute__((ext_vector_type(4)));

__device__ __forceinline__ float sigmoidf_(float x) {
    return 1.f / (1.f + __expf(-x));
}
__device__ __forceinline__ float tanhf_(float x) {
    float e = __expf(-2.f * fabsf(x));
    float t = (1.f - e) / (1.f + e);
    return x < 0.f ? -t : t;
}

// Gate col layout (n < 2048): octet o = n>>5, gate = (n>>3)&3, jj = n&7, j = o*8+jj.
// Any aligned 32-col group = [r(8) z(8) i_n(8) h_n(8)] for 8 consecutive j.
// n >= 2048: fc_w row (n-2048).
__global__ __launch_bounds__(256) void build_weights(
    const float* __restrict__ w_ih, const float* __restrict__ w_hh,
    const float* __restrict__ b_ih, const float* __restrict__ b_hh,
    const float* __restrict__ fc_w, const float* __restrict__ fc_b,
    __hip_bfloat16* __restrict__ Wt, __hip_bfloat16* __restrict__ W0t,
    float* __restrict__ bias, float* __restrict__ bias0)
{
    const int n = blockIdx.x;
    const int tid = threadIdx.x;
    __shared__ float wih_s[FF];
    const bool is_out = (n >= NGATE);
    int gate = 3, gidx = 0, f = 0;
    if (is_out) {
        f = n - NGATE;
    } else {
        int o = n >> 5;
        gate = (n >> 3) & 3;
        int j = o * 8 + (n & 7);
        gidx = (gate == 0) ? j : (gate == 1) ? (512 + j) : (1024 + j);
    }
    if (!is_out && gate != 3 && tid < FF) wih_s[tid] = w_ih[gidx * FF + tid];
    __syncthreads();

    for (int k = tid; k < HH; k += 256) {
        float w, w0;
        if (is_out) {
            w = fc_w[f * HH + k];
            w0 = 0.f;
        } else if (gate == 3) {
            w = w_hh[gidx * HH + k];
            w0 = w;
        } else {
            float comb = 0.f;
#pragma unroll 8
            for (int ff2 = 0; ff2 < FF; ++ff2) comb += wih_s[ff2] * fc_w[ff2 * HH + k];
            if (gate == 2) { w = comb; w0 = 0.f; }
            else { float whh = w_hh[gidx * HH + k]; w = whh + comb; w0 = whh; }
        }
        Wt[n * HH + k]  = __float2bfloat16(w);
        W0t[n * HH + k] = __float2bfloat16(w0);
    }
    if (tid == 0) {
        float b, b0;
        if (is_out) { b = fc_b[f]; b0 = 0.f; }
        else {
            float cb = 0.f;
            if (gate != 3)
                for (int ff2 = 0; ff2 < FF; ++ff2) cb += fc_b[ff2] * w_ih[gidx * FF + ff2];
            if (gate <= 1)      { float s2 = b_ih[gidx] + b_hh[gidx]; b = s2 + cb; b0 = s2; }
            else if (gate == 2) { b = b_ih[gidx] + cb; b0 = b_ih[gidx]; }
            else                { b = b_hh[gidx]; b0 = b_hh[gidx]; }
        }
        bias[n] = b; bias0[n] = b0;
    }
}

__global__ __launch_bounds__(256) void init_misc(
    const float* __restrict__ hidden, float* __restrict__ hf,
    __hip_bfloat16* __restrict__ hb, int* __restrict__ cnt, int nElem)
{
    int i = blockIdx.x * 256 + threadIdx.x;
    if (i < nElem) {
        float v = hidden[i];
        hf[i] = v;
        hb[i] = __float2bfloat16(v);
    }
    if (i < GRP * 128) cnt[i] = 0;
}

// Persistent GRU: 512 blocks = 16 row-groups x 32 col-blocks, 2 blocks/CU.
// Block tile 128 rows x 64 gate-cols; B tile LDS-resident (swizzled) all 96 steps.
// Waves: 2 row-halves x 2 col-halves; wave tile 64 rows x 32 cols (one j-octet:
// all 4 gates in-wave, combine via shfl_xor(8)). A (h) direct global->VGPR,
// prefetched one kt ahead. Group sync: agent-scope atomic counter per (g, s).
__global__ __launch_bounds__(256, 2) void gru_persist(
    const __hip_bfloat16* __restrict__ Wt, const __hip_bfloat16* __restrict__ W0t,
    const float* __restrict__ bias, const float* __restrict__ bias0,
    __hip_bfloat16* hb0, __hip_bfloat16* hb1,
    float* hf0, float* hf1, float* __restrict__ out, int* cnt)
{
    __shared__ __align__(16) int4 Bs[64 * 64];     // 64 KB persistent W tile
    __shared__ float fcred[8 * 256];               // 8 KB fc partial reduce

    const int tid = threadIdx.x;
    const int lane = tid & 63, w = tid >> 6;
    const int l15 = lane & 15, quad = lane >> 4;
    const int g = blockIdx.x & 15, c = blockIdx.x >> 4;
    const int rb = g * 128;
    const int n_base = c * 64;
    const int ch_half = w & 1;
    const int wr = rb + (w >> 1) * 64;
    const int nw = n_base + ch_half * 32;

    const short* wt  = (const short*)Wt;
    const short* w0t = (const short*)W0t;
    short8* bs8 = (short8*)Bs;

    // stage step-0 weights (W0: x=0 variant)
    for (int it = 0; it < 16; ++it) {
        int li = it * 256 + tid;
        int col = li >> 6, ch = li & 63;
        Bs[col * 64 + (ch ^ (col & 7))] = *(const int4*)&w0t[(n_base + col) * HH + ch * 8];
    }
    __syncthreads();

    // fc micro-tile assignment: 16 rows x 32 cols per block, K split over 4 waves
    const int rt_fc = c & 7, cp_fc = c >> 3;
    const int r0_fc = rb + rt_fc * 16;
    const int f0_fc = cp_fc * 32;

    const int lc0 = ch_half * 32 + l15;   // local B col, ct=0
    const int lc1 = lc0 + 16;
    const int cx0 = lc0 & 7, cx1 = lc1 & 7;
    int* cgrp = cnt + g * 128;

    for (int s = 0; s <= 96; ++s) {
        const short* hin  = (const short*)((s & 1) ? hb1 : hb0);
        const float* hinf = (s & 1) ? hf1 : hf0;
        __hip_bfloat16* hout = (s & 1) ? hb0 : hb1;
        float* houtf = (s & 1) ? hf0 : hf1;

        if (s >= 1) {
            // out[:, 96-s, :] tile = h_s[r0_fc:+16] @ fc_w.T[:, f0_fc:+32]
            const int tt = 96 - s;
            const int kw = w * 128;
            f32x4 p0 = {0.f, 0.f, 0.f, 0.f}, p1 = {0.f, 0.f, 0.f, 0.f};
            const short* arow  = hin + (size_t)(r0_fc + l15) * HH + kw + quad * 8;
            const short* brow0 = wt + (size_t)(NGATE + f0_fc + l15) * HH + kw + quad * 8;
            const short* brow1 = brow0 + 16 * HH;
#pragma unroll
            for (int k4 = 0; k4 < 4; ++k4) {
                short8 a  = *(const short8*)(arow  + k4 * 32);
                short8 b0 = *(const short8*)(brow0 + k4 * 32);
                short8 b1 = *(const short8*)(brow1 + k4 * 32);
                p0 = __builtin_amdgcn_mfma_f32_16x16x32_bf16(a, b0, p0, 0, 0, 0);
                p1 = __builtin_amdgcn_mfma_f32_16x16x32_bf16(a, b1, p1, 0, 0, 0);
            }
#pragma unroll
            for (int rg = 0; rg < 4; ++rg) {
                fcred[(w * 2 + 0) * 256 + (quad * 4 + rg) * 16 + l15] = p0[rg];
                fcred[(w * 2 + 1) * 256 + (quad * 4 + rg) * 16 + l15] = p1[rg];
            }
            __syncthreads();
#pragma unroll
            for (int e2 = 0; e2 < 2; ++e2) {
                int e = e2 * 256 + tid;
                int ct = e >> 8, idx = e & 255;
                int row = idx >> 4;
                float v = fcred[ct * 256 + idx] + fcred[512 + ct * 256 + idx]
                        + fcred[1024 + ct * 256 + idx] + fcred[1536 + ct * 256 + idx];
                int fcol = f0_fc + ct * 16 + (idx & 15);
                v += bias[NGATE + fcol];
                out[(size_t)(r0_fc + row) * (TT * FF) + tt * FF + fcol] = v;
            }
            __syncthreads();
        }
        if (s == 96) break;

        if (s == 1) {  // swap in full weights (x-path folded) after step 0
            for (int it = 0; it < 16; ++it) {
                int li = it * 256 + tid;
                int col = li >> 6, ch = li & 63;
                Bs[col * 64 + (ch ^ (col & 7))] = *(const int4*)&wt[(n_base + col) * HH + ch * 8];
            }
            __syncthreads();
        }

        // ---- gate GEMM: wave tile 64 rows x 32 cols ----
        const float* bp = (s == 0) ? bias0 : bias;
        f32x4 acc[4][2];
        {
            float b0v = bp[nw + l15];
            float b1v = bp[nw + 16 + l15];
#pragma unroll
            for (int rt = 0; rt < 4; ++rt) {
                acc[rt][0] = (f32x4){b0v, b0v, b0v, b0v};
                acc[rt][1] = (f32x4){b1v, b1v, b1v, b1v};
            }
        }
        const short* ap[4];
#pragma unroll
        for (int rt = 0; rt < 4; ++rt)
            ap[rt] = hin + (size_t)(wr + rt * 16 + l15) * HH + quad * 8;

        short8 acur[2][4], anxt[2][4];
#pragma unroll
        for (int ks = 0; ks < 2; ++ks)
#pragma unroll
            for (int rt = 0; rt < 4; ++rt)
                acur[ks][rt] = *(const short8*)(ap[rt] + ks * 32);

#pragma unroll
        for (int kt = 0; kt < 8; ++kt) {
            if (kt < 7) {
#pragma unroll
                for (int ks = 0; ks < 2; ++ks)
#pragma unroll
                    for (int rt = 0; rt < 4; ++rt)
                        anxt[ks][rt] = *(const short8*)(ap[rt] + (kt + 1) * 64 + ks * 32);
            }
#pragma unroll
            for (int ks = 0; ks < 2; ++ks) {
                int chnk = kt * 8 + ks * 4 + quad;
                short8 b0 = bs8[lc0 * 64 + (chnk ^ cx0)];
                short8 b1 = bs8[lc1 * 64 + (chnk ^ cx1)];
#pragma unroll
                for (int rt = 0; rt < 4; ++rt) {
                    acc[rt][0] = __builtin_amdgcn_mfma_f32_16x16x32_bf16(acur[ks][rt], b0, acc[rt][0], 0, 0, 0);
                    acc[rt][1] = __builtin_amdgcn_mfma_f32_16x16x32_bf16(acur[ks][rt], b1, acc[rt][1], 0, 0, 0);
                }
            }
#pragma unroll
            for (int ks = 0; ks < 2; ++ks)
#pragma unroll
                for (int rt = 0; rt < 4; ++rt)
                    acur[ks][rt] = anxt[ks][rt];
        }

        // ---- gate combine + h update (cols: [r(8) z(8)] | [i_n(8) h_n(8)]) ----
        const int jb = c * 16 + ch_half * 8;
#pragma unroll
        for (int rt = 0; rt < 4; ++rt) {
#pragma unroll
            for (int rg = 0; rg < 4; ++rg) {
                float a0 = acc[rt][0][rg], a1 = acc[rt][1][rg];
                float zsh  = __shfl_xor(a0, 8, 64);
                float hnsh = __shfl_xor(a1, 8, 64);
                if (l15 < 8) {
                    int row = wr + rt * 16 + quad * 4 + rg;
                    int j = jb + l15;
                    float r = sigmoidf_(a0);
                    float z = sigmoidf_(zsh);
                    float nv = tanhf_(a1 + r * hnsh);
                    float hold = hinf[(size_t)row * HH + j];
                    float hn2 = (1.f - z) * nv + z * hold;
                    houtf[(size_t)row * HH + j] = hn2;
                    hout[(size_t)row * HH + j] = __float2bfloat16(hn2);
                }
            }
        }

        // ---- row-group barrier (32 blocks) ----
        __threadfence();
        __syncthreads();
        if (tid == 0) {
            int* cc = cgrp + s;
            __hip_atomic_fetch_add(cc, 1, __ATOMIC_RELEASE, __HIP_MEMORY_SCOPE_AGENT);
            while (__hip_atomic_load(cc, __ATOMIC_ACQUIRE, __HIP_MEMORY_SCOPE_AGENT) < CPB)
                __builtin_amdgcn_s_sleep(2);
        }
        __syncthreads();
    }
}

extern "C" void kernel_launch(void* const* d_in, const int* in_sizes, int n_in,
                              void* d_out, int out_size, void* d_ws, size_t ws_size,
                              hipStream_t stream) {
    const float* hidden = (const float*)d_in[0];
    const float* w_ih   = (const float*)d_in[1];
    const float* w_hh   = (const float*)d_in[2];
    const float* b_ih   = (const float*)d_in[3];
    const float* b_hh   = (const float*)d_in[4];
    const float* fc_w   = (const float*)d_in[5];
    const float* fc_b   = (const float*)d_in[6];
    float* out = (float*)d_out;

    char* ws = (char*)d_ws;
    size_t off = 0;
    auto alloc = [&](size_t bytes) -> void* {
        void* p = ws + off;
        off += (bytes + 255) & ~(size_t)255;
        return p;
    };
    __hip_bfloat16* Wt  = (__hip_bfloat16*)alloc((size_t)NTOT * HH * 2);
    __hip_bfloat16* W0t = (__hip_bfloat16*)alloc((size_t)NTOT * HH * 2);
    float* bias  = (float*)alloc(NTOT * 4);
    float* bias0 = (float*)alloc(NTOT * 4);
    float* hf0 = (float*)alloc((size_t)BB * HH * 4);
    float* hf1 = (float*)alloc((size_t)BB * HH * 4);
    __hip_bfloat16* hb0 = (__hip_bfloat16*)alloc((size_t)BB * HH * 2);
    __hip_bfloat16* hb1 = (__hip_bfloat16*)alloc((size_t)BB * HH * 2);
    int* cnt = (int*)alloc(GRP * 128 * 4);

    build_weights<<<NTOT, 256, 0, stream>>>(w_ih, w_hh, b_ih, b_hh, fc_w, fc_b,
                                            Wt, W0t, bias, bias0);
    init_misc<<<(BB * HH + 255) / 256, 256, 0, stream>>>(hidden, hf0, hb0, cnt, BB * HH);
    gru_persist<<<512, 256, 0, stream>>>(Wt, W0t, bias, bias0,
                                         hb0, hb1, hf0, hf1, out, cnt);
}

// Round 3
// 1684.845 us; speedup vs baseline: 5.7934x; 5.7934x over previous
//
#include <hip/hip_runtime.h>
#include <hip/hip_bf16.h>

#define HH 512
#define FF 128
#define BB 2048
#define TT 96
#define NGATE 2048
#define NTOT 2176
#define GRP 16
#define CPB 32

typedef short short8 __attribute__((ext_vector_type(8)));
typedef float f32x4 __attribute__((ext_vector_type(4)));

__device__ __forceinline__ float sigmoidf_(float x) { return 1.f / (1.f + __expf(-x)); }
__device__ __forceinline__ float tanhf_(float x) {
    float e = __expf(-2.f * fabsf(x));
    float t = (1.f - e) / (1.f + e);
    return x < 0.f ? -t : t;
}

// byte offset of element (m, k) in a matrix stored as 16(m) x 32(k) MFMA-fragment
// tiles: lane = (m&15) + 16*((k>>3)&3) holds bytes [lane*16, lane*16+16) of a 1 KB tile.
__device__ __forceinline__ size_t frag_off(int m, int k, int K) {
    return (size_t)((m >> 4) * (K >> 5) + (k >> 5)) * 1024
         + (size_t)(((k >> 3) & 3) * 256 + (m & 15) * 16 + (k & 7) * 2);
}

__device__ __forceinline__ short bf16bits(float f) {
    __hip_bfloat16 b = __float2bfloat16(f);
    return *(short*)&b;
}

// Gate col layout (n < 2048): octet o=n>>5, gate=(n>>3)&3, j=o*8+(n&7):
// each aligned 32-col group = [r(8) z(8) i_n(8) h_n(8)] for 8 consecutive j.
// Weights written in B-fragment order (frag_off). n>=2048: fc_w row -> Wfc.
__global__ __launch_bounds__(256) void build_weights(
    const float* __restrict__ w_ih, const float* __restrict__ w_hh,
    const float* __restrict__ b_ih, const float* __restrict__ b_hh,
    const float* __restrict__ fc_w, const float* __restrict__ fc_b,
    char* __restrict__ Wg, char* __restrict__ W0g, char* __restrict__ Wfc,
    float* __restrict__ bias, float* __restrict__ bias0)
{
    const int n = blockIdx.x;
    const int tid = threadIdx.x;
    __shared__ float wih_s[FF];
    const bool is_out = (n >= NGATE);
    int gate = 3, gidx = 0, f = 0;
    if (is_out) {
        f = n - NGATE;
    } else {
        int o = n >> 5;
        gate = (n >> 3) & 3;
        int j = o * 8 + (n & 7);
        gidx = (gate == 0) ? j : (gate == 1) ? (512 + j) : (1024 + j);
    }
    if (!is_out && gate != 3 && tid < FF) wih_s[tid] = w_ih[gidx * FF + tid];
    __syncthreads();

    for (int k = tid; k < HH; k += 256) {
        float w, w0;
        if (is_out) {
            w = fc_w[f * HH + k];
            w0 = 0.f;
        } else if (gate == 3) {
            w = w_hh[gidx * HH + k];
            w0 = w;
        } else {
            float comb = 0.f;
#pragma unroll 8
            for (int ff2 = 0; ff2 < FF; ++ff2) comb += wih_s[ff2] * fc_w[ff2 * HH + k];
            if (gate == 2) { w = comb; w0 = 0.f; }
            else { float whh = w_hh[gidx * HH + k]; w = whh + comb; w0 = whh; }
        }
        if (is_out) {
            *(short*)(Wfc + frag_off(f, k, HH)) = bf16bits(w);
        } else {
            *(short*)(Wg  + frag_off(n, k, HH)) = bf16bits(w);
            *(short*)(W0g + frag_off(n, k, HH)) = bf16bits(w0);
        }
    }
    if (tid == 0 && !is_out) {
        float b, b0;
        float cb = 0.f;
        if (gate != 3)
            for (int ff2 = 0; ff2 < FF; ++ff2) cb += fc_b[ff2] * w_ih[gidx * FF + ff2];
        if (gate <= 1)      { float s2 = b_ih[gidx] + b_hh[gidx]; b = s2 + cb; b0 = s2; }
        else if (gate == 2) { b = b_ih[gidx] + cb; b0 = b_ih[gidx]; }
        else                { b = b_hh[gidx]; b0 = b_hh[gidx]; }
        bias[n] = b; bias0[n] = b0;
    }
}

// hidden (fp32 row-major) -> h_0 bf16 in fragment order; zero sync counters.
__global__ __launch_bounds__(256) void init_misc(
    const float* __restrict__ hidden, char* __restrict__ hfrag, int* __restrict__ cnt)
{
    int i = blockIdx.x * 256 + threadIdx.x;  // 131072 granules of 8 k-elements
    int row = i >> 6, k0 = (i & 63) << 3;
    short8 v;
#pragma unroll
    for (int t = 0; t < 8; ++t) v[t] = bf16bits(hidden[(size_t)row * HH + k0 + t]);
    *(short8*)(hfrag + frag_off(row, k0, HH)) = v;
    if (i < GRP * 128) cnt[i] = 0;
}

#define GLD64(p) __hip_atomic_load((const unsigned long long*)(p), __ATOMIC_RELAXED, __HIP_MEMORY_SCOPE_AGENT)
#define GST64(p, v) __hip_atomic_store((unsigned long long*)(p), (v), __ATOMIC_RELAXED, __HIP_MEMORY_SCOPE_AGENT)

// Persistent GRU. 512 blocks = 16 row-groups x 32 col-blocks, guaranteed 2/CU
// (no LDS pressure, VGPR<=256 via launch_bounds). h exchanged through L3 via
// relaxed agent atomics in MFMA-fragment order: no fences, no L2 flush ever.
// fp32 carry h lives in the owning block's VGPRs. Per-step group barrier:
// vmcnt drain + one relaxed atomic add + spin.
__global__ __launch_bounds__(256, 2) void gru_persist(
    const char* __restrict__ Wg, const char* __restrict__ W0g, const char* __restrict__ Wfc,
    const float* __restrict__ bias, const float* __restrict__ bias0,
    const float* __restrict__ fc_b, const float* __restrict__ hidden,
    char* __restrict__ hfrag0, char* __restrict__ hfrag1,
    float* __restrict__ out, int* __restrict__ cnt)
{
    __shared__ __align__(16) short hpack[2][128][16];  // 8 KB h transpose scratch

    const int tid = threadIdx.x;
    const int lane = tid & 63, w = tid >> 6;
    const int l15 = lane & 15, quad = lane >> 4;
    const int g = blockIdx.x & 15, c = blockIdx.x >> 4;
    const int wr = g * 128 + w * 32;        // wave's first row

    // group-local fc tile: 64 of the group's 128 waves each own 16 rows x 16 cols
    const int fidx = c * 4 + w;
    const bool fc_act = fidx < 64;
    const int rtfc = g * 8 + (fidx >> 3), ctfc = fidx & 7;

    // fp32 carry h for this block's (row, j) ownership — never leaves VGPRs
    float carry[2][2][4];
    if (l15 < 8) {
#pragma unroll
        for (int rt = 0; rt < 2; ++rt)
#pragma unroll
            for (int og = 0; og < 2; ++og)
#pragma unroll
                for (int rg = 0; rg < 4; ++rg) {
                    int row = wr + rt * 16 + quad * 4 + rg;
                    int j = c * 16 + og * 8 + l15;
                    carry[rt][og][rg] = hidden[(size_t)row * HH + j];
                }
    }

    int* cc = cnt + g * 128;

    for (int s = 0; s <= 96; ++s) {
        const char* hin = (s & 1) ? hfrag1 : hfrag0;
        char* hout = (s & 1) ? hfrag0 : hfrag1;

        // ---- fc projection of h_s -> out[:, 96-s, :] (group-local rows) ----
        if (s >= 1 && fc_act) {
            const char* ab = hin + (size_t)rtfc * 16 * 1024 + lane * 16;
            const char* bb = Wfc + (size_t)ctfc * 16 * 1024 + lane * 16;
            f32x4 p = {0.f, 0.f, 0.f, 0.f};
            union { unsigned long long u[2]; short8 v; } fa0, fa1;
            short8 fb0, fb1;
            fa0.u[0] = GLD64(ab); fa0.u[1] = GLD64(ab + 8);
            fb0 = *(const short8*)bb;
            fa1.u[0] = GLD64(ab + 1024); fa1.u[1] = GLD64(ab + 1032);
            fb1 = *(const short8*)(bb + 1024);
            for (int it = 0; it < 8; ++it) {
                p = __builtin_amdgcn_mfma_f32_16x16x32_bf16(fa0.v, fb0, p, 0, 0, 0);
                if (it < 7) {
                    const char* pa = ab + (size_t)(2 * it + 2) * 1024;
                    fa0.u[0] = GLD64(pa); fa0.u[1] = GLD64(pa + 8);
                    fb0 = *(const short8*)(bb + (size_t)(2 * it + 2) * 1024);
                }
                p = __builtin_amdgcn_mfma_f32_16x16x32_bf16(fa1.v, fb1, p, 0, 0, 0);
                if (it < 7) {
                    const char* pa = ab + (size_t)(2 * it + 3) * 1024;
                    fa1.u[0] = GLD64(pa); fa1.u[1] = GLD64(pa + 8);
                    fb1 = *(const short8*)(bb + (size_t)(2 * it + 3) * 1024);
                }
            }
            const int tt = 96 - s;
            const int col = ctfc * 16 + l15;
            const float bv = fc_b[col];
#pragma unroll
            for (int rg = 0; rg < 4; ++rg) {
                int row = rtfc * 16 + quad * 4 + rg;
                out[(size_t)row * (TT * FF) + tt * FF + col] = p[rg] + bv;
            }
        }
        if (s == 96) break;

        // ---- gate GEMM: 128 rows x 64 gate cols, K=512, frags direct ----
        const char* Wsel = s ? Wg : W0g;
        const float* bsel = s ? bias : bias0;

        const char* aA[2];
#pragma unroll
        for (int rt = 0; rt < 2; ++rt)
            aA[rt] = hin + (size_t)(g * 8 + w * 2 + rt) * 16 * 1024 + lane * 16;
        const char* bB[4];
#pragma unroll
        for (int ct = 0; ct < 4; ++ct)
            bB[ct] = Wsel + (size_t)(c * 4 + ct) * 16 * 1024 + lane * 16;

        f32x4 acc[2][4];
#pragma unroll
        for (int ct = 0; ct < 4; ++ct) {
            float bv = bsel[c * 64 + ct * 16 + l15];
            acc[0][ct] = (f32x4){bv, bv, bv, bv};
            acc[1][ct] = acc[0][ct];
        }

        union { unsigned long long u[2]; short8 v; } A0[2], A1[2];
        short8 B0[4], B1[4];
#pragma unroll
        for (int rt = 0; rt < 2; ++rt) {
            A0[rt].u[0] = GLD64(aA[rt]);        A0[rt].u[1] = GLD64(aA[rt] + 8);
            A1[rt].u[0] = GLD64(aA[rt] + 1024); A1[rt].u[1] = GLD64(aA[rt] + 1032);
        }
#pragma unroll
        for (int ct = 0; ct < 4; ++ct) {
            B0[ct] = *(const short8*)(bB[ct]);
            B1[ct] = *(const short8*)(bB[ct] + 1024);
        }

        for (int it = 0; it < 8; ++it) {
#pragma unroll
            for (int rt = 0; rt < 2; ++rt)
#pragma unroll
                for (int ct = 0; ct < 4; ++ct)
                    acc[rt][ct] = __builtin_amdgcn_mfma_f32_16x16x32_bf16(A0[rt].v, B0[ct], acc[rt][ct], 0, 0, 0);
            if (it < 7) {
                size_t ko = (size_t)(2 * it + 2) * 1024;
#pragma unroll
                for (int rt = 0; rt < 2; ++rt) {
                    A0[rt].u[0] = GLD64(aA[rt] + ko); A0[rt].u[1] = GLD64(aA[rt] + ko + 8);
                }
#pragma unroll
                for (int ct = 0; ct < 4; ++ct) B0[ct] = *(const short8*)(bB[ct] + ko);
            }
#pragma unroll
            for (int rt = 0; rt < 2; ++rt)
#pragma unroll
                for (int ct = 0; ct < 4; ++ct)
                    acc[rt][ct] = __builtin_amdgcn_mfma_f32_16x16x32_bf16(A1[rt].v, B1[ct], acc[rt][ct], 0, 0, 0);
            if (it < 7) {
                size_t ko = (size_t)(2 * it + 3) * 1024;
#pragma unroll
                for (int rt = 0; rt < 2; ++rt) {
                    A1[rt].u[0] = GLD64(aA[rt] + ko); A1[rt].u[1] = GLD64(aA[rt] + ko + 8);
                }
#pragma unroll
                for (int ct = 0; ct < 4; ++ct) B1[ct] = *(const short8*)(bB[ct] + ko);
            }
        }

        // ---- gate combine + h update; stage bf16 h_new into LDS ----
#pragma unroll
        for (int rt = 0; rt < 2; ++rt)
#pragma unroll
            for (int og = 0; og < 2; ++og)
#pragma unroll
                for (int rg = 0; rg < 4; ++rg) {
                    float arz = acc[rt][2 * og][rg], anh = acc[rt][2 * og + 1][rg];
                    float zsh = __shfl_xor(arz, 8, 64);
                    float hsh = __shfl_xor(anh, 8, 64);
                    if (l15 < 8) {
                        float r = sigmoidf_(arz);
                        float z = sigmoidf_(zsh);
                        float nv = tanhf_(anh + r * hsh);
                        float hn = (1.f - z) * nv + z * carry[rt][og][rg];
                        carry[rt][og][rg] = hn;
                        hpack[s & 1][w * 32 + rt * 16 + quad * 4 + rg][og * 8 + l15] = bf16bits(hn);
                    }
                }
        __syncthreads();

        // ---- pack-store h_new in fragment order (2 coalesced b64 atomics) ----
        {
            int lrow = tid >> 1, half = tid & 1;
            int4 v = *(const int4*)&hpack[s & 1][lrow][half * 8];
            size_t off = (size_t)((g * 8 + (lrow >> 4)) * 16 + (c >> 1)) * 1024
                       + (size_t)((((c << 1) + half) & 3) * 256 + (lrow & 15) * 16);
            GST64(hout + off,     ((const unsigned long long*)&v)[0]);
            GST64(hout + off + 8, ((const unsigned long long*)&v)[1]);
        }

        // ---- row-group barrier: drain stores, one relaxed atomic, spin ----
        asm volatile("s_waitcnt vmcnt(0)" ::: "memory");
        __syncthreads();
        if (tid == 0) {
            __hip_atomic_fetch_add(cc + s, 1, __ATOMIC_RELAXED, __HIP_MEMORY_SCOPE_AGENT);
            while (__hip_atomic_load(cc + s, __ATOMIC_RELAXED, __HIP_MEMORY_SCOPE_AGENT) < CPB)
                __builtin_amdgcn_s_sleep(2);
        }
        __syncthreads();
        asm volatile("" ::: "memory");
    }
}

extern "C" void kernel_launch(void* const* d_in, const int* in_sizes, int n_in,
                              void* d_out, int out_size, void* d_ws, size_t ws_size,
                              hipStream_t stream) {
    const float* hidden = (const float*)d_in[0];
    const float* w_ih   = (const float*)d_in[1];
    const float* w_hh   = (const float*)d_in[2];
    const float* b_ih   = (const float*)d_in[3];
    const float* b_hh   = (const float*)d_in[4];
    const float* fc_w   = (const float*)d_in[5];
    const float* fc_b   = (const float*)d_in[6];
    float* out = (float*)d_out;

    char* ws = (char*)d_ws;
    size_t off = 0;
    auto alloc = [&](size_t bytes) -> void* {
        void* p = ws + off;
        off += (bytes + 255) & ~(size_t)255;
        return p;
    };
    char* Wg   = (char*)alloc((size_t)NGATE * HH * 2);
    char* W0g  = (char*)alloc((size_t)NGATE * HH * 2);
    char* Wfc  = (char*)alloc((size_t)FF * HH * 2);
    float* bias  = (float*)alloc(NGATE * 4);
    float* bias0 = (float*)alloc(NGATE * 4);
    char* hfrag0 = (char*)alloc((size_t)BB * HH * 2);
    char* hfrag1 = (char*)alloc((size_t)BB * HH * 2);
    int* cnt = (int*)alloc(GRP * 128 * 4);

    build_weights<<<NTOT, 256, 0, stream>>>(w_ih, w_hh, b_ih, b_hh, fc_w, fc_b,
                                            Wg, W0g, Wfc, bias, bias0);
    init_misc<<<(BB * HH / 8 + 255) / 256, 256, 0, stream>>>(hidden, hfrag0, cnt);
    gru_persist<<<512, 256, 0, stream>>>(Wg, W0g, Wfc, bias, bias0, fc_b, hidden,
                                         hfrag0, hfrag1, out, cnt);
}